// Round 3
// baseline (3670.664 us; speedup 1.0000x reference)
//
#include <hip/hip_runtime.h>
#include <hip/hip_bf16.h>

typedef unsigned short u16;
typedef unsigned int   u32;

typedef __attribute__((ext_vector_type(8))) short short8;
typedef __attribute__((ext_vector_type(4))) float f32x4;

__device__ __forceinline__ float bf2f(u16 u) {
    u32 x = ((u32)u) << 16;
    return __builtin_bit_cast(float, x);
}
__device__ __forceinline__ u16 f2bf(float f) {
    u32 u = __builtin_bit_cast(u32, f);
    u32 r = (u + 0x7FFFu + ((u >> 16) & 1u)) >> 16;
    return (u16)r;
}
__device__ __forceinline__ u32 pack2(float a, float b) {
    return (u32)f2bf(a) | ((u32)f2bf(b) << 16);
}

// ---------------------------------------------------------------------------
// Dtype detector: reads first 16384 u16 words of X. bf16 data -> ~100% sane
// exponent fields; fp32 data reinterpreted as u16 -> ~57%. flags[0]=1 => fp32.
// flags[1] is a guaranteed-zero word used by consumers needing "always bf16".
// ---------------------------------------------------------------------------
__global__ void detect_kernel(const u16* __restrict__ X, int* __restrict__ flags) {
    __shared__ int cnt[256];
    int c = 0;
    for (int i = threadIdx.x; i < 16384; i += 256) {
        u16 v = X[i];
        int e = (v >> 7) & 0xFF;
        c += (e >= 104 && e <= 140) ? 1 : 0;
    }
    cnt[threadIdx.x] = c;
    __syncthreads();
    for (int s = 128; s > 0; s >>= 1) {
        if (threadIdx.x < s) cnt[threadIdx.x] += cnt[threadIdx.x + s];
        __syncthreads();
    }
    if (threadIdx.x == 0) {
        flags[0] = (cnt[0] < 14746) ? 1 : 0;   // <90% sane => fp32
        flags[1] = 0;
    }
}

// X canonicalization: only does work when input is fp32 (copies to bf16 XC).
__global__ __launch_bounds__(256) void convert_x(const float* __restrict__ Xf,
                                                 u16* __restrict__ XC,
                                                 const int* __restrict__ flags, int n) {
    if (flags[0] == 0) return;
    int i = (blockIdx.x * 256 + threadIdx.x) * 8;
    if (i >= n) return;
    float4 a = *(const float4*)(Xf + i);
    float4 b = *(const float4*)(Xf + i + 4);
    uint4 o;
    o.x = pack2(a.x, a.y); o.y = pack2(a.z, a.w);
    o.z = pack2(b.x, b.y); o.w = pack2(b.z, b.w);
    *(uint4*)(XC + i) = o;
}

// mask canonicalization to fp32 (always runs; tiny).
__global__ void convert_mask(const void* __restrict__ m, float* __restrict__ MC,
                             const int* __restrict__ flags, int n) {
    int i = blockIdx.x * 256 + threadIdx.x;
    if (i >= n) return;
    MC[i] = flags[0] ? ((const float*)m)[i] : bf2f(((const u16*)m)[i]);
}

// ---------------------------------------------------------------------------
// GEMM: C(MxN, ldc) = A(MxK, bf16, lda) * Bt(NxK, bf16, ldb)^T
// 128x128 tile, BK=32, 4 waves (2x2), 16x16x32 bf16 MFMA, register staging.
// A chosen between A0/A1 by aselp[0]; C stored bf16 or fp32 per ofp[0].
// ---------------------------------------------------------------------------
__global__ __launch_bounds__(256) void gemm_bt(
    const u16* __restrict__ A0, const u16* __restrict__ A1, int lda,
    const u16* __restrict__ Bt, int ldb,
    void* __restrict__ C, int ldc,
    int Mtiles, int K,
    const int* __restrict__ aselp, const int* __restrict__ ofp) {
    __shared__ char smem[16384];

    const u16* A = aselp[0] ? A1 : A0;

    const int tid = threadIdx.x;
    const int w = tid >> 6, lane = tid & 63;
    const int mt = blockIdx.x % Mtiles;
    const int nt = blockIdx.x / Mtiles;
    const int m0 = mt << 7, n0 = nt << 7;
    const int wm = w >> 1, wn = w & 1;

    f32x4 acc[4][4] = {};

    // staging: row rr = w*16 + lane/4 (plus +64 for second store),
    // LDS slot s = lane&3 holds global chunk cg = s ^ swz(row), swz(r)=(r>>1)&3
    const int rr = w * 16 + (lane >> 2);
    const int cg = (lane & 3) ^ ((lane >> 3) & 3);

    const u16* gA0 = A + (m0 + rr) * lda + cg * 8;
    const u16* gA1 = A + (m0 + rr + 64) * lda + cg * 8;
    const u16* gB0 = Bt + (n0 + rr) * ldb + cg * 8;
    const u16* gB1 = Bt + (n0 + rr + 64) * ldb + cg * 8;

    uint4* lA0 = (uint4*)(smem + w * 1024 + lane * 16);
    uint4* lA1 = (uint4*)(smem + 4096 + w * 1024 + lane * 16);
    uint4* lB0 = (uint4*)(smem + 8192 + w * 1024 + lane * 16);
    uint4* lB1 = (uint4*)(smem + 12288 + w * 1024 + lane * 16);

    // fragment reads: row = wm*64 + mi*16 + (lane&15), chunk q = lane>>4,
    // slot = q ^ ((lane>>1)&3)
    const int fr_a = (wm << 6) + (lane & 15);
    const int fr_b = (wn << 6) + (lane & 15);
    const int sl = (lane >> 4) ^ ((lane >> 1) & 3);
    const char* pA = smem + fr_a * 64 + sl * 16;
    const char* pB = smem + 8192 + fr_b * 64 + sl * 16;

    for (int kt = 0; kt < K; kt += 32) {
        uint4 va0 = *(const uint4*)(gA0 + kt);
        uint4 va1 = *(const uint4*)(gA1 + kt);
        uint4 vb0 = *(const uint4*)(gB0 + kt);
        uint4 vb1 = *(const uint4*)(gB1 + kt);
        *lA0 = va0;
        *lA1 = va1;
        *lB0 = vb0;
        *lB1 = vb1;
        __syncthreads();
        short8 af[4], bfv[4];
#pragma unroll
        for (int i = 0; i < 4; ++i) {
            af[i]  = *(const short8*)(pA + i * 1024);
            bfv[i] = *(const short8*)(pB + i * 1024);
        }
#pragma unroll
        for (int mi = 0; mi < 4; ++mi) {
#pragma unroll
            for (int ni = 0; ni < 4; ++ni) {
                acc[mi][ni] = __builtin_amdgcn_mfma_f32_16x16x32_bf16(
                    af[mi], bfv[ni], acc[mi][ni], 0, 0, 0);
            }
        }
        __syncthreads();
    }

    // epilogue: repack 32-row strips through LDS; store bf16 or fp32 per flag
    const int out_fp32 = ofp[0];
    float* fb = (float*)smem;
    const int lrow = tid >> 3, cgp = tid & 7;
#pragma unroll 1
    for (int mi = 0; mi < 4; ++mi) {
#pragma unroll
        for (int ni = 0; ni < 4; ++ni) {
#pragma unroll
            for (int r = 0; r < 4; ++r) {
                int lr = wm * 16 + ((lane >> 4) << 2) + r;
                int lc = wn * 64 + ni * 16 + (lane & 15);
                fb[lr * 128 + lc] = acc[mi][ni][r];
            }
        }
        __syncthreads();
        int grow = (lrow < 16) ? (mi * 16 + lrow) : (48 + mi * 16 + lrow);
        const float* srcp = fb + lrow * 128 + cgp * 16;
        if (out_fp32) {
            float4* dst = (float4*)((float*)C + (size_t)(m0 + grow) * ldc + n0 + cgp * 16);
            dst[0] = make_float4(srcp[0], srcp[1], srcp[2], srcp[3]);
            dst[1] = make_float4(srcp[4], srcp[5], srcp[6], srcp[7]);
            dst[2] = make_float4(srcp[8], srcp[9], srcp[10], srcp[11]);
            dst[3] = make_float4(srcp[12], srcp[13], srcp[14], srcp[15]);
        } else {
            u32 o0 = pack2(srcp[0], srcp[1]);
            u32 o1 = pack2(srcp[2], srcp[3]);
            u32 o2 = pack2(srcp[4], srcp[5]);
            u32 o3 = pack2(srcp[6], srcp[7]);
            u32 o4 = pack2(srcp[8], srcp[9]);
            u32 o5 = pack2(srcp[10], srcp[11]);
            u32 o6 = pack2(srcp[12], srcp[13]);
            u32 o7 = pack2(srcp[14], srcp[15]);
            uint4* dst = (uint4*)((u16*)C + (size_t)(m0 + grow) * ldc + n0 + cgp * 16);
            dst[0] = make_uint4(o0, o1, o2, o3);
            dst[1] = make_uint4(o4, o5, o6, o7);
        }
        __syncthreads();
    }
}

// ---------------------------------------------------------------------------
// Transpose weights into (N,K) row-major bf16, dual-dtype source reads.
// W1T rows [0,128)=Wq^T, [128,256)=Wk^T, [256,1280)=Wv^T; OpT = o_proj^T.
// ---------------------------------------------------------------------------
__device__ __forceinline__ u16 rd_elem(const void* s, int idx, int fp32) {
    return fp32 ? f2bf(((const float*)s)[idx]) : ((const u16*)s)[idx];
}

__global__ void transpose_k(const void* __restrict__ Wq, const void* __restrict__ Wk,
                            const void* __restrict__ Wv, const void* __restrict__ Op,
                            u16* __restrict__ W1T, u16* __restrict__ OpT,
                            const int* __restrict__ flags) {
    int fp32 = flags[0];
    int id = blockIdx.x;
    const void* src; u16* dst; int Nc, mid;
    if (id < 128)       { src = Wq; dst = W1T;               Nc = 128;  mid = id; }
    else if (id < 256)  { src = Wk; dst = W1T + 128 * 1024;  Nc = 128;  mid = id - 128; }
    else if (id < 1280) { src = Wv; dst = W1T + 256 * 1024;  Nc = 1024; mid = id - 256; }
    else                { src = Op; dst = OpT;               Nc = 1024; mid = id - 1280; }
    int kt = mid & 31, nt = mid >> 5;
    __shared__ u16 tile[32][33];
    int x = threadIdx.x & 31, y0 = threadIdx.x >> 5;
#pragma unroll
    for (int yy = 0; yy < 4; ++yy) {
        int y = y0 * 4 + yy;
        tile[y][x] = rd_elem(src, (kt * 32 + y) * Nc + nt * 32 + x, fp32);
    }
    __syncthreads();
#pragma unroll
    for (int yy = 0; yy < 4; ++yy) {
        int y = y0 * 4 + yy;
        dst[(nt * 32 + y) * 1024 + kt * 32 + x] = tile[x][y];
    }
}

// ---------------------------------------------------------------------------
// Partial max of K over 256-row chunks: Pmax[b][chunk][l]
// ---------------------------------------------------------------------------
__global__ __launch_bounds__(256) void maxpart_kernel(const u16* __restrict__ QKV,
                                                      float* __restrict__ Pmax) {
    int bid = blockIdx.x;            // b*32 + chunk
    int b = bid >> 5, chunk = bid & 31;
    int tid = threadIdx.x;
    int l = tid & 127, half = tid >> 7;
    float mx = -3.0e38f;
    int t0 = chunk * 256;
    for (int i = half; i < 256; i += 2) {
        int m = b * 8192 + t0 + i;
        mx = fmaxf(mx, bf2f(QKV[(size_t)m * 1280 + 128 + l]));
    }
    __shared__ float sm[256];
    sm[tid] = mx;
    __syncthreads();
    if (tid < 128) Pmax[bid * 128 + tid] = fmaxf(sm[tid], sm[tid + 128]);
}

__global__ void maxreduce_kernel(const float* __restrict__ Pmax, float* __restrict__ Kmax) {
    int tid = threadIdx.x;           // 512: b*128 + l
    float mx = -3.0e38f;
    int b = tid >> 7;
    int l = tid & 127;
    for (int c = 0; c < 32; ++c) mx = fmaxf(mx, Pmax[(b * 32 + c) * 128 + l]);
    Kmax[tid] = mx;
}

// ---------------------------------------------------------------------------
// Partial Kv/Ksum over 256-row chunks. Block = ((b*16+h)*32 + chunk), 4 waves.
// ---------------------------------------------------------------------------
__global__ __launch_bounds__(256) void kvpart_kernel(const u16* __restrict__ QKV,
                                                     const float* __restrict__ MC,
                                                     const float* __restrict__ Kmax,
                                                     float* __restrict__ Kvp,
                                                     float* __restrict__ Ksp) {
    int bid = blockIdx.x;
    int chunk = bid & 31;
    int bh = bid >> 5;
    int h = bh & 15, b = bh >> 4;
    int w = threadIdx.x >> 6, lane = threadIdx.x & 63;

    float mx[8];
#pragma unroll
    for (int l = 0; l < 8; ++l) mx[l] = Kmax[b * 128 + h * 8 + l];

    float kv[8] = {0, 0, 0, 0, 0, 0, 0, 0};
    float ks[8] = {0, 0, 0, 0, 0, 0, 0, 0};
    int t0 = chunk * 256;
    for (int i = 0; i < 64; ++i) {
        int t = t0 + w + i * 4;
        int m = b * 8192 + t;
        const u16* row = QKV + (size_t)m * 1280;
        float v = bf2f(row[256 + h * 64 + lane]);
        uint4 kq = *(const uint4*)(row + 128 + h * 8);
        float msk = MC[b * 8192 + t];
        float vm = v * msk;
        float kf[8];
        kf[0] = __builtin_bit_cast(float, kq.x << 16);
        kf[1] = __builtin_bit_cast(float, kq.x & 0xffff0000u);
        kf[2] = __builtin_bit_cast(float, kq.y << 16);
        kf[3] = __builtin_bit_cast(float, kq.y & 0xffff0000u);
        kf[4] = __builtin_bit_cast(float, kq.z << 16);
        kf[5] = __builtin_bit_cast(float, kq.z & 0xffff0000u);
        kf[6] = __builtin_bit_cast(float, kq.w << 16);
        kf[7] = __builtin_bit_cast(float, kq.w & 0xffff0000u);
#pragma unroll
        for (int l = 0; l < 8; ++l) {
            float e = __expf(kf[l] - mx[l]) * msk;   // exp(K-max)*mask
            kv[l] += e * vm;                         // * (V*mask)
            ks[l] += e;
        }
    }
    __shared__ float red[4][8][64];
    __shared__ float redks[4][8];
#pragma unroll
    for (int l = 0; l < 8; ++l) red[w][l][lane] = kv[l];
    if (lane == 0) {
#pragma unroll
        for (int l = 0; l < 8; ++l) redks[w][l] = ks[l];
    }
    __syncthreads();
    int tid = threadIdx.x;
    for (int c = tid; c < 512; c += 256) {
        int l = c >> 6, d = c & 63;
        Kvp[bid * 512 + c] = red[0][l][d] + red[1][l][d] + red[2][l][d] + red[3][l][d];
    }
    if (tid < 8) Ksp[bid * 8 + tid] = redks[0][tid] + redks[1][tid] + redks[2][tid] + redks[3][tid];
}

__global__ void kvreduce_kernel(const float* __restrict__ Kvp, const float* __restrict__ Ksp,
                                float* __restrict__ Kv) {
    int bh = blockIdx.x;             // 64
    int tid = threadIdx.x;           // 512 = l*64+d
    int l = tid >> 6;
    float s = 0.f, ks = 0.f;
    for (int c = 0; c < 32; ++c) {
        s += Kvp[(bh * 32 + c) * 512 + tid];
        ks += Ksp[(bh * 32 + c) * 8 + l];
    }
    Kv[bh * 512 + tid] = s / ks;
}

// ---------------------------------------------------------------------------
// y[m, h*64+d] = softmax_l(Q[m,h,:]) @ Kv[b,h,l,d]; in-place over V region.
// ---------------------------------------------------------------------------
__global__ __launch_bounds__(256) void y_kernel(u16* __restrict__ QKV,
                                                const float* __restrict__ Kv) {
    int bid = blockIdx.x;            // b*64 + chunk(128 rows)
    int b = bid >> 6, chunk = bid & 63;
    int w = threadIdx.x >> 6, lane = threadIdx.x & 63;
    int hh = w & 1;
    int rp = w >> 1;
    int hloc = lane >> 3;
    int h = hh * 8 + hloc;
    int dg = lane & 7;

    float4 kva[8], kvb[8];
    const float* kvp = Kv + (b * 16 + h) * 512 + dg * 8;
#pragma unroll
    for (int l = 0; l < 8; ++l) {
        kva[l] = *(const float4*)(kvp + l * 64);
        kvb[l] = *(const float4*)(kvp + l * 64 + 4);
    }
    int lgrp = lane & 56;
    for (int i = 0; i < 64; ++i) {
        int t = chunk * 128 + i * 2 + rp;
        int m = b * 8192 + t;
        u16* row = QKV + (size_t)m * 1280;
        float qv = bf2f(row[hh * 64 + lane]);
        float qm = qv;
        qm = fmaxf(qm, __shfl_xor(qm, 1));
        qm = fmaxf(qm, __shfl_xor(qm, 2));
        qm = fmaxf(qm, __shfl_xor(qm, 4));
        float e = __expf(qv - qm);
        float s = e;
        s += __shfl_xor(s, 1);
        s += __shfl_xor(s, 2);
        s += __shfl_xor(s, 4);
        float qs = e / s;
        float4 a0 = {0.f, 0.f, 0.f, 0.f}, a1 = {0.f, 0.f, 0.f, 0.f};
#pragma unroll
        for (int l = 0; l < 8; ++l) {
            float ql = __shfl(qs, lgrp + l);
            a0.x += ql * kva[l].x; a0.y += ql * kva[l].y;
            a0.z += ql * kva[l].z; a0.w += ql * kva[l].w;
            a1.x += ql * kvb[l].x; a1.y += ql * kvb[l].y;
            a1.z += ql * kvb[l].z; a1.w += ql * kvb[l].w;
        }
        uint4 o;
        o.x = pack2(a0.x, a0.y);
        o.y = pack2(a0.z, a0.w);
        o.z = pack2(a1.x, a1.y);
        o.w = pack2(a1.z, a1.w);
        *(uint4*)(row + 256 + h * 64 + dg * 8) = o;
    }
}

// ---------------------------------------------------------------------------
// Workspace layout (bytes)
// ---------------------------------------------------------------------------
#define OFF_FLAG ((size_t)0)                        // 2 ints
#define OFF_W1T  ((size_t)1024)                     // 1280*1024*2 = 2,621,440
#define OFF_OPT  ((size_t)2622464)                  // 1024*1024*2 = 2,097,152
#define OFF_PMAX ((size_t)4719616)                  // 16384*4 = 65,536
#define OFF_KMAX ((size_t)4785152)                  // 512*4 = 2,048
#define OFF_KVP  ((size_t)4787200)                  // 2048*512*4 = 4,194,304
#define OFF_KSP  ((size_t)8981504)                  // 2048*8*4 = 65,536
#define OFF_KV   ((size_t)9047040)                  // 64*512*4 = 131,072
#define OFF_MC   ((size_t)9178112)                  // 32768*4 = 131,072
#define OFF_XC   ((size_t)9309184)                  // 33554432*2 = 67,108,864
#define OFF_QKV  ((size_t)76418048)                 // 32768*1280*2 = 83,886,080
// total = 160,304,128 bytes

extern "C" void kernel_launch(void* const* d_in, const int* in_sizes, int n_in,
                              void* d_out, int out_size, void* d_ws, size_t ws_size,
                              hipStream_t stream) {
    const u16* X   = (const u16*)d_in[0];
    const void* msk = d_in[1];
    const void* Wk  = d_in[2];
    const void* Wq  = d_in[3];
    const void* Wv  = d_in[4];
    const void* Op  = d_in[5];

    char* ws = (char*)d_ws;
    int*   FLAGS = (int*)(ws + OFF_FLAG);
    u16*   W1T  = (u16*)(ws + OFF_W1T);
    u16*   OPT  = (u16*)(ws + OFF_OPT);
    float* PMAX = (float*)(ws + OFF_PMAX);
    float* KMAX = (float*)(ws + OFF_KMAX);
    float* KVP  = (float*)(ws + OFF_KVP);
    float* KSP  = (float*)(ws + OFF_KSP);
    float* KV   = (float*)(ws + OFF_KV);
    float* MC   = (float*)(ws + OFF_MC);
    u16*   XC   = (u16*)(ws + OFF_XC);
    u16*   QKV  = (u16*)(ws + OFF_QKV);

    // 0) detect input dtype (flags[0]=1 -> fp32), flags[1]=0 always
    detect_kernel<<<1, 256, 0, stream>>>(X, FLAGS);
    // 0b) canonicalize X (no-op if bf16) and mask (always fp32 canonical)
    convert_x<<<16384, 256, 0, stream>>>((const float*)d_in[0], XC, FLAGS, 33554432);
    convert_mask<<<128, 256, 0, stream>>>(msk, MC, FLAGS, 32768);
    // 1) transpose weights to (N,K) bf16 (dual-dtype reads)
    transpose_k<<<2304, 256, 0, stream>>>(Wq, Wk, Wv, Op, W1T, OPT, FLAGS);
    // 2) fused QKV projection: QKV[m,0:128)=Q, [128:256)=K, [256:1280)=V
    gemm_bt<<<2560, 256, 0, stream>>>(X, XC, 1024, W1T, 1024, QKV, 1280, 256, 1024,
                                      FLAGS, FLAGS + 1);
    // 3) global max of K over T
    maxpart_kernel<<<128, 256, 0, stream>>>(QKV, PMAX);
    maxreduce_kernel<<<1, 512, 0, stream>>>(PMAX, KMAX);
    // 4) Kv state + Ksum
    kvpart_kernel<<<2048, 256, 0, stream>>>(QKV, MC, KMAX, KVP, KSP);
    kvreduce_kernel<<<64, 512, 0, stream>>>(KVP, KSP, KV);
    // 5) y = softmax(Q) @ Kv, in-place over V region
    y_kernel<<<256, 256, 0, stream>>>(QKV, KV);
    // 6) out = y @ o_proj (output dtype per detected flag)
    gemm_bt<<<2048, 256, 0, stream>>>(QKV + 256, QKV + 256, 1280, OPT, 1024,
                                      d_out, 1024, 256, 1024, FLAGS + 1, FLAGS);
}